// Round 1
// baseline (725.075 us; speedup 1.0000x reference)
//
#include <hip/hip_runtime.h>

// ============================================================================
// FFT conv, register-resident four-step factorization: 8192 = 16 x 16 x 32.
// 256 threads/block, 32 complex values per thread in registers.
// Forward: F1(16pt over n1, upper half zero) -> T1 -> F2(16pt over n2) -> T2
//          -> F3(32pt over n3, in regs)
// Pointwise (in regs, Kf stored in matching slot order, skip x*D folded as
// spectral +d/N) -> inverse mirror.
// Only 4 LDS transposes total, all access patterns conflict-free:
//   T1 layout: idx = 512*k1 + 32*n2 + n3      (linear)
//   T2 layout: idx = 512*k1 + 32*k2 + (n3^k1) (XOR swizzle; addr = vx ^ n3)
// ============================================================================

#define LCONV 4096
#define NFFT  8192
#define NT    256
#define HCH   1024
#define BATCH 16

#define C707 0.70710678118654752f
#define C16A 0.92387953251128674f   /* cos(pi/8)   */
#define S16A 0.38268343236508977f   /* sin(pi/8)   */
#define C32A 0.98078528040323044f   /* cos(pi/16)  */
#define S32A 0.19509032201612827f   /* sin(pi/16)  */
#define C32B 0.83146961230254524f   /* cos(3pi/16) */
#define S32B 0.55557023301960222f   /* sin(3pi/16) */

#define A256f  (-0.0245436926061702596f)   /* -2pi/256  */
#define A512f  (-0.0122718463030851298f)   /* -2pi/512  */
#define A8192f (-7.66990393942820615e-4f)  /* -2pi/8192 */

static __device__ __forceinline__ float2 cadd(float2 a, float2 b){ return make_float2(a.x+b.x, a.y+b.y); }
static __device__ __forceinline__ float2 csub(float2 a, float2 b){ return make_float2(a.x-b.x, a.y-b.y); }
static __device__ __forceinline__ float2 cmul(float2 a, float2 b){ return make_float2(a.x*b.x - a.y*b.y, a.x*b.y + a.y*b.x); }
// multiply by e^{-i pi/4}, -i, e^{-3i pi/4} and conjugates
static __device__ __forceinline__ float2 mW81 (float2 d){ return make_float2( C707*(d.x+d.y),  C707*(d.y-d.x)); }
static __device__ __forceinline__ float2 mNI  (float2 d){ return make_float2( d.y, -d.x); }
static __device__ __forceinline__ float2 mW83 (float2 d){ return make_float2( C707*(d.y-d.x), -C707*(d.x+d.y)); }
static __device__ __forceinline__ float2 mW81c(float2 d){ return make_float2( C707*(d.x-d.y),  C707*(d.x+d.y)); }
static __device__ __forceinline__ float2 mPI  (float2 d){ return make_float2(-d.y,  d.x); }
static __device__ __forceinline__ float2 mW83c(float2 d){ return make_float2(-C707*(d.x+d.y),  C707*(d.x-d.y)); }

// DIF-8 network, natural inputs; output slot s holds X_{rev3[s]}, rev3={0,4,2,6,1,5,3,7}
static __device__ __forceinline__ void net8_fwd(float2 a[8]) {
    float2 t0=cadd(a[0],a[4]), t4=csub(a[0],a[4]);
    float2 t1=cadd(a[1],a[5]), t5=mW81(csub(a[1],a[5]));
    float2 t2=cadd(a[2],a[6]), t6=mNI (csub(a[2],a[6]));
    float2 t3=cadd(a[3],a[7]), t7=mW83(csub(a[3],a[7]));
    float2 u0=cadd(t0,t2), u2=csub(t0,t2);
    float2 u1=cadd(t1,t3), u3=mNI(csub(t1,t3));
    float2 u4=cadd(t4,t6), u6=csub(t4,t6);
    float2 u5=cadd(t5,t7), u7=mNI(csub(t5,t7));
    a[0]=cadd(u0,u1); a[1]=csub(u0,u1);
    a[2]=cadd(u2,u3); a[3]=csub(u2,u3);
    a[4]=cadd(u4,u5); a[5]=csub(u4,u5);
    a[6]=cadd(u6,u7); a[7]=csub(u6,u7);
}
// conjugate network (computes sum c_n w^{+nk}), natural in -> rev3 slot out
static __device__ __forceinline__ void net8_inv(float2 a[8]) {
    float2 t0=cadd(a[0],a[4]), t4=csub(a[0],a[4]);
    float2 t1=cadd(a[1],a[5]), t5=mW81c(csub(a[1],a[5]));
    float2 t2=cadd(a[2],a[6]), t6=mPI  (csub(a[2],a[6]));
    float2 t3=cadd(a[3],a[7]), t7=mW83c(csub(a[3],a[7]));
    float2 u0=cadd(t0,t2), u2=csub(t0,t2);
    float2 u1=cadd(t1,t3), u3=mPI(csub(t1,t3));
    float2 u4=cadd(t4,t6), u6=csub(t4,t6);
    float2 u5=cadd(t5,t7), u7=mPI(csub(t5,t7));
    a[0]=cadd(u0,u1); a[1]=csub(u0,u1);
    a[2]=cadd(u2,u3); a[3]=csub(u2,u3);
    a[4]=cadd(u4,u5); a[5]=csub(u4,u5);
    a[6]=cadd(u6,u7); a[7]=csub(u6,u7);
}

// 16-pt DIF fwd: natural in -> slot s holds k = K16[s] = {0,8,4,12,2,10,6,14,1,9,5,13,3,11,7,15}
static __device__ __forceinline__ void fft16_fwd(float2 a[16]) {
    float2 lo[8], hi[8];
#pragma unroll
    for (int n=0;n<8;++n){ lo[n]=cadd(a[n],a[n+8]); hi[n]=csub(a[n],a[n+8]); }
    hi[1]=cmul(hi[1],make_float2( C16A,-S16A));
    hi[2]=mW81(hi[2]);
    hi[3]=cmul(hi[3],make_float2( S16A,-C16A));
    hi[4]=mNI(hi[4]);
    hi[5]=cmul(hi[5],make_float2(-S16A,-C16A));
    hi[6]=mW83(hi[6]);
    hi[7]=cmul(hi[7],make_float2(-C16A,-S16A));
    net8_fwd(lo); net8_fwd(hi);
#pragma unroll
    for (int s=0;s<8;++s){ a[s]=lo[s]; a[8+s]=hi[s]; }
}
// 16-pt inverse DFT, natural in -> slot s holds n = K16[s]
static __device__ __forceinline__ void fft16_inv_nat(float2 a[16]) {
    float2 lo[8], hi[8];
#pragma unroll
    for (int n=0;n<8;++n){ lo[n]=cadd(a[n],a[n+8]); hi[n]=csub(a[n],a[n+8]); }
    hi[1]=cmul(hi[1],make_float2( C16A, S16A));
    hi[2]=mW81c(hi[2]);
    hi[3]=cmul(hi[3],make_float2( S16A, C16A));
    hi[4]=mPI(hi[4]);
    hi[5]=cmul(hi[5],make_float2(-S16A, C16A));
    hi[6]=mW83c(hi[6]);
    hi[7]=cmul(hi[7],make_float2(-C16A, S16A));
    net8_inv(lo); net8_inv(hi);
#pragma unroll
    for (int s=0;s<8;++s){ a[s]=lo[s]; a[8+s]=hi[s]; }
}
// 32-pt DIF fwd: natural in; slots 0..15 hold even k = 2*K16[s], 16..31 hold 2*K16[s]+1
static __device__ __forceinline__ void fft32_fwd(float2 a[32]) {
    float2 lo[16], hi[16];
#pragma unroll
    for (int n=0;n<16;++n){ lo[n]=cadd(a[n],a[n+16]); hi[n]=csub(a[n],a[n+16]); }
    hi[ 1]=cmul(hi[ 1],make_float2( C32A,-S32A));
    hi[ 2]=cmul(hi[ 2],make_float2( C16A,-S16A));
    hi[ 3]=cmul(hi[ 3],make_float2( C32B,-S32B));
    hi[ 4]=mW81(hi[ 4]);
    hi[ 5]=cmul(hi[ 5],make_float2( S32B,-C32B));
    hi[ 6]=cmul(hi[ 6],make_float2( S16A,-C16A));
    hi[ 7]=cmul(hi[ 7],make_float2( S32A,-C32A));
    hi[ 8]=mNI(hi[ 8]);
    hi[ 9]=cmul(hi[ 9],make_float2(-S32A,-C32A));
    hi[10]=cmul(hi[10],make_float2(-S16A,-C16A));
    hi[11]=cmul(hi[11],make_float2(-S32B,-C32B));
    hi[12]=mW83(hi[12]);
    hi[13]=cmul(hi[13],make_float2(-C32B,-S32B));
    hi[14]=cmul(hi[14],make_float2(-C16A,-S16A));
    hi[15]=cmul(hi[15],make_float2(-C32A,-S32A));
    fft16_fwd(lo); fft16_fwd(hi);
#pragma unroll
    for (int s=0;s<16;++s){ a[s]=lo[s]; a[16+s]=hi[s]; }
}

// inverse 8-pt DFT: input slots in rev3 order (slot s holds k=rev3[s]) -> natural output
static __device__ __forceinline__ void inv8_r2n(const float2 b[8], float2 o[8]) {
    float2 e0=cadd(b[0],b[1]), e1=csub(b[0],b[1]);
    float2 f0=cadd(b[2],b[3]), f1=mPI(csub(b[2],b[3]));
    float2 E0=cadd(e0,f0), E2=csub(e0,f0);
    float2 E1=cadd(e1,f1), E3=csub(e1,f1);
    float2 g0=cadd(b[4],b[5]), g1=csub(b[4],b[5]);
    float2 h0=cadd(b[6],b[7]), h1=mPI(csub(b[6],b[7]));
    float2 O0=cadd(g0,h0), O2=csub(g0,h0);
    float2 O1=cadd(g1,h1), O3=csub(g1,h1);
    float2 T0=O0, T1=mW81c(O1), T2=mPI(O2), T3=mW83c(O3);
    o[0]=cadd(E0,T0); o[4]=csub(E0,T0);
    o[1]=cadd(E1,T1); o[5]=csub(E1,T1);
    o[2]=cadd(E2,T2); o[6]=csub(E2,T2);
    o[3]=cadd(E3,T3); o[7]=csub(E3,T3);
}
// inverse 16-pt DFT: input slots in K16 order -> natural output
static __device__ __forceinline__ void inv16_r2n(const float2 a[16], float2 o[16]) {
    float2 E[8], O[8];
    inv8_r2n(a, E); inv8_r2n(a+8, O);
    float2 T[8];
    T[0]=O[0];
    T[1]=cmul(O[1],make_float2( C16A, S16A));
    T[2]=mW81c(O[2]);
    T[3]=cmul(O[3],make_float2( S16A, C16A));
    T[4]=mPI(O[4]);
    T[5]=cmul(O[5],make_float2(-S16A, C16A));
    T[6]=mW83c(O[6]);
    T[7]=cmul(O[7],make_float2(-C16A, S16A));
#pragma unroll
    for (int n=0;n<8;++n){ o[n]=cadd(E[n],T[n]); o[n+8]=csub(E[n],T[n]); }
}
// inverse 32-pt DFT: input slots in fft32_fwd order -> natural output
static __device__ __forceinline__ void inv32_r2n(const float2 a[32], float2 o[32]) {
    float2 E[16], O[16], T;
    inv16_r2n(a, E); inv16_r2n(a+16, O);
    T=O[0];                                  o[ 0]=cadd(E[ 0],T); o[16]=csub(E[ 0],T);
    T=cmul(O[ 1],make_float2( C32A, S32A)); o[ 1]=cadd(E[ 1],T); o[17]=csub(E[ 1],T);
    T=cmul(O[ 2],make_float2( C16A, S16A)); o[ 2]=cadd(E[ 2],T); o[18]=csub(E[ 2],T);
    T=cmul(O[ 3],make_float2( C32B, S32B)); o[ 3]=cadd(E[ 3],T); o[19]=csub(E[ 3],T);
    T=mW81c(O[ 4]);                          o[ 4]=cadd(E[ 4],T); o[20]=csub(E[ 4],T);
    T=cmul(O[ 5],make_float2( S32B, C32B)); o[ 5]=cadd(E[ 5],T); o[21]=csub(E[ 5],T);
    T=cmul(O[ 6],make_float2( S16A, C16A)); o[ 6]=cadd(E[ 6],T); o[22]=csub(E[ 6],T);
    T=cmul(O[ 7],make_float2( S32A, C32A)); o[ 7]=cadd(E[ 7],T); o[23]=csub(E[ 7],T);
    T=mPI(O[ 8]);                            o[ 8]=cadd(E[ 8],T); o[24]=csub(E[ 8],T);
    T=cmul(O[ 9],make_float2(-S32A, C32A)); o[ 9]=cadd(E[ 9],T); o[25]=csub(E[ 9],T);
    T=cmul(O[10],make_float2(-S16A, C16A)); o[10]=cadd(E[10],T); o[26]=csub(E[10],T);
    T=cmul(O[11],make_float2(-S32B, C32B)); o[11]=cadd(E[11],T); o[27]=csub(E[11],T);
    T=mW83c(O[12]);                          o[12]=cadd(E[12],T); o[28]=csub(E[12],T);
    T=cmul(O[13],make_float2(-C32B, S32B)); o[13]=cadd(E[13],T); o[29]=csub(E[13],T);
    T=cmul(O[14],make_float2(-C16A, S16A)); o[14]=cadd(E[14],T); o[30]=csub(E[14],T);
    T=cmul(O[15],make_float2(-C32A, S32A)); o[15]=cadd(E[15],T); o[31]=csub(E[15],T);
}

// F1: 16-pt over n1 with n1>=8 inputs zero (zero padding), twiddle W_256^{n2*k1},
// write T1 at idx = 512*k1 + col (col = 32*n2 + n3).
static __device__ __forceinline__ void f1_stage(float2* __restrict__ z, const float2 d[8],
                                                int n2, int col)
{
    constexpr int rev3[8] = {0,4,2,6,1,5,3,7};
    float2 lo[8], hi[8];
    lo[0]=d[0]; hi[0]=d[0];
    lo[1]=d[1]; hi[1]=cmul(d[1],make_float2( C16A,-S16A));
    lo[2]=d[2]; hi[2]=mW81(d[2]);
    lo[3]=d[3]; hi[3]=cmul(d[3],make_float2( S16A,-C16A));
    lo[4]=d[4]; hi[4]=mNI(d[4]);
    lo[5]=d[5]; hi[5]=cmul(d[5],make_float2(-S16A,-C16A));
    lo[6]=d[6]; hi[6]=mW83(d[6]);
    lo[7]=d[7]; hi[7]=cmul(d[7],make_float2(-C16A,-S16A));
    net8_fwd(lo); net8_fwd(hi);
    const float a1 = A256f * (float)n2;
    float2 stp2; __sincosf(2.f*a1, &stp2.y, &stp2.x);
    float2 ce = make_float2(1.f, 0.f);
    float2 co; __sincosf(a1, &co.y, &co.x);
#pragma unroll
    for (int m=0;m<8;++m){
        if (m==4){ __sincosf(8.f*a1, &ce.y, &ce.x); __sincosf(9.f*a1, &co.y, &co.x); }
        const int s2 = rev3[m];   // slot holding k=2m (rev3 is an involution)
        z[512*(2*m)   + col] = cmul(lo[s2], ce);
        z[512*(2*m+1) + col] = cmul(hi[s2], co);
        ce = cmul(ce, stp2); co = cmul(co, stp2);
    }
}

// F2 output: twiddle W_8192^{n3*(k1+16*k2)} and write T2 (swizzled idx = 512k1+32k2+(n3^k1))
static __device__ __forceinline__ void f2_write(float2* __restrict__ z, const float2 a[16],
                                                int k1, int n3)
{
    constexpr int K16[16]={0,8,4,12,2,10,6,14,1,9,5,13,3,11,7,15};
    const float ab = A8192f * (float)(n3*k1);
    const float as = A512f  * (float)n3;
    float2 stp; __sincosf(as, &stp.y, &stp.x);
    float2 cur; __sincosf(ab, &cur.y, &cur.x);
    const int wb = 512*k1 + (n3 ^ k1);
#pragma unroll
    for (int j=0;j<16;++j){
        if (j==8) __sincosf(ab + 8.f*as, &cur.y, &cur.x);
        z[wb + 32*j] = cmul(a[K16[j]], cur);   // K16 is an involution: slot for k2=j
        cur = cmul(cur, stp);
    }
}

// F2' output: twiddle e^{+2pi i k1 (32*n2+n3)/8192} and write T1' (idx = 512k1+32n2+n3)
static __device__ __forceinline__ void f2i_write(float2* __restrict__ z, const float2 a[16],
                                                 int k1, int n3)
{
    constexpr int K16[16]={0,8,4,12,2,10,6,14,1,9,5,13,3,11,7,15};
    const float ab = -A8192f * (float)(n3*k1);
    const float as = -A256f  * (float)k1;
    float2 stp; __sincosf(as, &stp.y, &stp.x);
    float2 cur; __sincosf(ab, &cur.y, &cur.x);
    const int wb = 512*k1 + n3;
#pragma unroll
    for (int j=0;j<16;++j){
        if (j==8) __sincosf(ab + 8.f*as, &cur.y, &cur.x);
        z[wb + 32*j] = cmul(a[K16[j]], cur);
        cur = cmul(cur, stp);
    }
}

// ============================================================================
__global__ __launch_bounds__(NT) void kfft_kernel(const float* __restrict__ k,
                                                  float2* __restrict__ Kf)
{
    __shared__ float2 z[NFFT];
    const int h = blockIdx.x, t = threadIdx.x;
    const int n3 = t & 31, g = t >> 5;
    const float* __restrict__ kr = k + (size_t)h * LCONV;

#pragma unroll
    for (int s=0;s<2;++s){
        const int n2 = 2*g + s;
        const int col = 32*n2 + n3;
        float2 d[8];
#pragma unroll
        for (int n=0;n<8;++n) d[n] = make_float2(kr[512*n + col], 0.f);
        f1_stage(z, d, n2, col);
    }
    __syncthreads();

    float2 a0[16], a1[16];
    {
        const int b0 = 512*(2*g) + n3, b1 = b0 + 512;
#pragma unroll
        for (int n=0;n<16;++n) a0[n] = z[b0 + 32*n];
#pragma unroll
        for (int n=0;n<16;++n) a1[n] = z[b1 + 32*n];
    }
    fft16_fwd(a0); fft16_fwd(a1);
    __syncthreads();
    f2_write(z, a0, 2*g,   n3);
    f2_write(z, a1, 2*g+1, n3);
    __syncthreads();

    {
        const int k1 = t & 15, k2 = t >> 4;
        const int vx = 513*k1 + 32*k2;           // low 5 bits = k1 -> addr(n3) = vx ^ n3
        float2 b[32];
#pragma unroll
        for (int q=0;q<32;++q) b[q] = z[vx ^ q];
        fft32_fwd(b);
        float2* __restrict__ op = Kf + (size_t)h*NFFT + t;
        const float sc = 1.0f/(float)NFFT;       // fold 1/N into Kf
#pragma unroll
        for (int q=0;q<32;++q)
            op[256*q] = make_float2(b[q].x*sc, b[q].y*sc);
    }
}

__global__ __launch_bounds__(NT) void conv_kernel(const float* __restrict__ x,
                                                  const float2* __restrict__ Kf,
                                                  const float* __restrict__ Dv,
                                                  float* __restrict__ y)
{
    __shared__ float2 z[NFFT];
    constexpr int rev3[8]={0,4,2,6,1,5,3,7};

    // bijective XCD swizzle: 8 blocks sharing one h land on one XCD (bid%8 = XCD id)
    const int bid = blockIdx.x;
    const int r  = bid & 7;
    const int jj = bid >> 3;
    const int h  = r*(HCH/8) + (jj >> 3);
    const int pb = jj & 7;
    const int t  = threadIdx.x;
    const int n3 = t & 31, g = t >> 5;

    const float* __restrict__ x0 = x + ((size_t)(2*pb  )*HCH + h)*LCONV;
    const float* __restrict__ x1 = x + ((size_t)(2*pb+1)*HCH + h)*LCONV;

    // ---- F1: batch pair packed as re/im; zero padding folded (n1>=8 inputs are 0) ----
#pragma unroll
    for (int s=0;s<2;++s){
        const int n2 = 2*g + s;
        const int col = 32*n2 + n3;
        float2 d[8];
#pragma unroll
        for (int n=0;n<8;++n)
            d[n] = make_float2(x0[512*n + col], x1[512*n + col]);
        f1_stage(z, d, n2, col);
    }
    __syncthreads();

    // ---- F2 ----
    float2 a0[16], a1[16];
    {
        const int b0 = 512*(2*g) + n3, b1 = b0 + 512;
#pragma unroll
        for (int n=0;n<16;++n) a0[n] = z[b0 + 32*n];
#pragma unroll
        for (int n=0;n<16;++n) a1[n] = z[b1 + 32*n];
    }
    fft16_fwd(a0); fft16_fwd(a1);
    __syncthreads();
    f2_write(z, a0, 2*g,   n3);
    f2_write(z, a1, 2*g+1, n3);
    __syncthreads();

    // ---- F3 + pointwise (skip x*D folded as +d/N) + inverse F3' ----
    {
        const int k1 = t & 15, k2 = t >> 4;
        const float2* __restrict__ kfp = Kf + (size_t)h*NFFT + t;
        float2 kf[32];
#pragma unroll
        for (int q=0;q<32;++q) kf[q] = kfp[256*q];       // coalesced, slot-order match
        const float dN = Dv[h] * (1.0f/(float)NFFT);
        const int vx = 513*k1 + 32*k2;
        float2 b[32];
#pragma unroll
        for (int q=0;q<32;++q) b[q] = z[vx ^ q];
        fft32_fwd(b);
#pragma unroll
        for (int q=0;q<32;++q)
            b[q] = cmul(b[q], make_float2(kf[q].x + dN, kf[q].y));
        float2 c[32];
        inv32_r2n(b, c);
        // twiddle e^{+2pi i k2 q/512}; write back to the SAME addresses (no barrier needed)
        const float as = -A512f * (float)k2;
        float2 stp; __sincosf(as, &stp.y, &stp.x);
        float2 cur = make_float2(1.f, 0.f);
#pragma unroll
        for (int q=0;q<32;++q){
            if (q && (q&7)==0) __sincosf(as*(float)q, &cur.y, &cur.x);
            z[vx ^ q] = cmul(c[q], cur);
            cur = cmul(cur, stp);
        }
    }
    __syncthreads();

    // ---- F2' ----
    {
        const int k1a = 2*g, k1b = 2*g+1;
        const int b0 = 512*k1a + (n3 ^ k1a);
        const int b1 = 512*k1b + (n3 ^ k1b);
#pragma unroll
        for (int n=0;n<16;++n) a0[n] = z[b0 + 32*n];
#pragma unroll
        for (int n=0;n<16;++n) a1[n] = z[b1 + 32*n];
    }
    fft16_inv_nat(a0); fft16_inv_nat(a1);
    __syncthreads();
    f2i_write(z, a0, 2*g,   n3);
    f2i_write(z, a1, 2*g+1, n3);
    __syncthreads();

    // ---- F1': pruned inverse 16 over k1 (only n1 < 8 needed) + store ----
    float* __restrict__ y0 = y + ((size_t)(2*pb  )*HCH + h)*LCONV;
    float* __restrict__ y1 = y + ((size_t)(2*pb+1)*HCH + h)*LCONV;
#pragma unroll
    for (int s=0;s<2;++s){
        const int n2 = 2*g + s;
        const int col = 32*n2 + n3;
        float2 ev[8], od[8];
#pragma unroll
        for (int m=0;m<8;++m){
            ev[m] = z[512*(2*m)   + col];
            od[m] = z[512*(2*m+1) + col];
        }
        net8_inv(ev); net8_inv(od);
#pragma unroll
        for (int n1=0;n1<8;++n1){
            float2 E  = ev[rev3[n1]];             // slot s2 holds n=rev3[s2]; involution
            float2 Ov = od[rev3[n1]];
            float2 T;
            if      (n1==0) T = Ov;
            else if (n1==1) T = cmul(Ov, make_float2( C16A, S16A));
            else if (n1==2) T = mW81c(Ov);
            else if (n1==3) T = cmul(Ov, make_float2( S16A, C16A));
            else if (n1==4) T = mPI(Ov);
            else if (n1==5) T = cmul(Ov, make_float2(-S16A, C16A));
            else if (n1==6) T = mW83c(Ov);
            else            T = cmul(Ov, make_float2(-C16A, S16A));
            float2 o = cadd(E, T);
            y0[512*n1 + col] = o.x;
            y1[512*n1 + col] = o.y;
        }
    }
}

extern "C" void kernel_launch(void* const* d_in, const int* in_sizes, int n_in,
                              void* d_out, int out_size, void* d_ws, size_t ws_size,
                              hipStream_t stream) {
    const float* x  = (const float*)d_in[0];
    const float* k  = (const float*)d_in[1];
    const float* Dv = (const float*)d_in[2];
    float* y   = (float*)d_out;
    float2* Kf = (float2*)d_ws;   // HCH * NFFT * 8 B = 64 MB

    kfft_kernel<<<HCH, NT, 0, stream>>>(k, Kf);
    conv_kernel<<<HCH * (BATCH/2), NT, 0, stream>>>(x, Kf, Dv, y);
}

// Round 2
// 649.330 us; speedup vs baseline: 1.1166x; 1.1166x over previous
//
#include <hip/hip_runtime.h>

#define LCONV 4096
#define NFFT 8192
#define NT 512
#define HCH 1024
#define BATCH 16
#define PI_F 3.14159265358979f
#define C707 0.70710678118654752f
#define C16A 0.92387953251128674f   /* cos(pi/8) */
#define S16A 0.38268343236508977f   /* sin(pi/8) */

// XOR swizzle on complex index: kills LDS bank conflicts for all stage strides.
#define SW(i) ((i) ^ (((i) >> 4) & 15))

__device__ __forceinline__ float2 cadd(float2 a, float2 b){ return make_float2(a.x+b.x, a.y+b.y); }
__device__ __forceinline__ float2 csub(float2 a, float2 b){ return make_float2(a.x-b.x, a.y-b.y); }
__device__ __forceinline__ float2 cmul(float2 a, float2 b){ return make_float2(a.x*b.x - a.y*b.y, a.x*b.y + a.y*b.x); }
// multiply by e^{-i pi/4}, -i, e^{-3i pi/4} and conjugates
__device__ __forceinline__ float2 mW81 (float2 d){ return make_float2( C707*(d.x+d.y),  C707*(d.y-d.x)); }
__device__ __forceinline__ float2 mNI  (float2 d){ return make_float2( d.y, -d.x); }
__device__ __forceinline__ float2 mW83 (float2 d){ return make_float2( C707*(d.y-d.x), -C707*(d.x+d.y)); }
__device__ __forceinline__ float2 mW81c(float2 d){ return make_float2( C707*(d.x-d.y),  C707*(d.x+d.y)); }
__device__ __forceinline__ float2 mPI  (float2 d){ return make_float2(-d.y,  d.x); }
__device__ __forceinline__ float2 mW83c(float2 d){ return make_float2(-C707*(d.x+d.y),  C707*(d.x-d.y)); }

// DIF-8 network, natural inputs a[0..7]; output slot s holds b_{rev3[s]}, rev3={0,4,2,6,1,5,3,7}
__device__ __forceinline__ void net8_fwd(float2 a[8]) {
    float2 t0=cadd(a[0],a[4]), t4=csub(a[0],a[4]);
    float2 t1=cadd(a[1],a[5]), t5=mW81(csub(a[1],a[5]));
    float2 t2=cadd(a[2],a[6]), t6=mNI (csub(a[2],a[6]));
    float2 t3=cadd(a[3],a[7]), t7=mW83(csub(a[3],a[7]));
    float2 u0=cadd(t0,t2), u2=csub(t0,t2);
    float2 u1=cadd(t1,t3), u3=mNI(csub(t1,t3));
    float2 u4=cadd(t4,t6), u6=csub(t4,t6);
    float2 u5=cadd(t5,t7), u7=mNI(csub(t5,t7));
    a[0]=cadd(u0,u1); a[1]=csub(u0,u1);
    a[2]=cadd(u2,u3); a[3]=csub(u2,u3);
    a[4]=cadd(u4,u5); a[5]=csub(u4,u5);
    a[6]=cadd(u6,u7); a[7]=csub(u6,u7);
}
// conjugate network (computes B_k = sum c_n w^{+nk}), same slot mapping
__device__ __forceinline__ void net8_inv(float2 a[8]) {
    float2 t0=cadd(a[0],a[4]), t4=csub(a[0],a[4]);
    float2 t1=cadd(a[1],a[5]), t5=mW81c(csub(a[1],a[5]));
    float2 t2=cadd(a[2],a[6]), t6=mPI  (csub(a[2],a[6]));
    float2 t3=cadd(a[3],a[7]), t7=mW83c(csub(a[3],a[7]));
    float2 u0=cadd(t0,t2), u2=csub(t0,t2);
    float2 u1=cadd(t1,t3), u3=mPI(csub(t1,t3));
    float2 u4=cadd(t4,t6), u6=csub(t4,t6);
    float2 u5=cadd(t5,t7), u7=mPI(csub(t5,t7));
    a[0]=cadd(u0,u1); a[1]=csub(u0,u1);
    a[2]=cadd(u2,u3); a[3]=csub(u2,u3);
    a[4]=cadd(u4,u5); a[5]=csub(u4,u5);
    a[6]=cadd(u6,u7); a[7]=csub(u6,u7);
}

template<int M, bool INV>
__device__ __forceinline__ void bf8(float2* z, int idx, const float2 w[8]) {
    float2 a[8];
    if (!INV) {
#pragma unroll
        for (int q = 0; q < 8; ++q) a[q] = z[SW(idx + q*M)];
        net8_fwd(a);
        z[SW(idx      )] = a[0];
        z[SW(idx + 4*M)] = cmul(a[1], w[4]);
        z[SW(idx + 2*M)] = cmul(a[2], w[2]);
        z[SW(idx + 6*M)] = cmul(a[3], w[6]);
        z[SW(idx + 1*M)] = cmul(a[4], w[1]);
        z[SW(idx + 5*M)] = cmul(a[5], w[5]);
        z[SW(idx + 3*M)] = cmul(a[6], w[3]);
        z[SW(idx + 7*M)] = cmul(a[7], w[7]);
    } else {
        a[0] = z[SW(idx)];
#pragma unroll
        for (int q = 1; q < 8; ++q) a[q] = cmul(z[SW(idx + q*M)], w[q]);
        net8_inv(a);
        z[SW(idx      )] = a[0];
        z[SW(idx + 4*M)] = a[1];
        z[SW(idx + 2*M)] = a[2];
        z[SW(idx + 6*M)] = a[3];
        z[SW(idx + 1*M)] = a[4];
        z[SW(idx + 5*M)] = a[5];
        z[SW(idx + 3*M)] = a[6];
        z[SW(idx + 7*M)] = a[7];
    }
}

// Radix-8 stage at sub-size M. Twiddles: output q scaled by e^{∓2πi q j/(8M)}.
// NT=512: each thread does 2 butterflies (1024 total per stage).
template<int M, bool INV>
__device__ __forceinline__ void stage8(float2* z, int tid) {
    __syncthreads();
    const float ang = (INV ? 2.0f : -2.0f) * PI_F / (8.0f * (float)M);
    if (M == 1024) {
        float2 w1, wstep;
        __sincosf(ang * (float)tid, &w1.y, &w1.x);
        __sincosf(ang * 512.0f, &wstep.y, &wstep.x);
#pragma unroll
        for (int s = 0; s < 2; ++s) {
            float2 w[8];
            w[0] = make_float2(1.f, 0.f);
            w[1] = w1;
#pragma unroll
            for (int q = 2; q < 8; ++q) w[q] = cmul(w[q-1], w1);
            bf8<M, INV>(z, tid + 512*s, w);
            w1 = cmul(w1, wstep);
        }
    } else {
        const int LOG2M = (M == 128) ? 7 : 4;
        int j  = tid & (M - 1);
        int g0 = tid >> LOG2M;
        float2 w[8];
        w[0] = make_float2(1.f, 0.f);
        __sincosf(ang * (float)j, &w[1].y, &w[1].x);
#pragma unroll
        for (int q = 2; q < 8; ++q) w[q] = cmul(w[q-1], w[1]);
#pragma unroll
        for (int s = 0; s < 2; ++s) {
            int base = (g0 + (NT / M) * s) * (8 * M);
            bf8<M, INV>(z, base + j, w);
        }
    }
}

// Final radix-16 on contiguous 16-chunks (twiddle-free externally; W16 constants internal).
// Output within chunk is in NATURAL spectral order. NT=512: one chunk per thread.
template<bool INV>
__device__ __forceinline__ void stage16(float2* z, int tid) {
    __syncthreads();
    {
        int b = tid * 16;
        float2 a[16];
#pragma unroll
        for (int e = 0; e < 16; ++e) a[e] = z[SW(b + e)];
        float2 lo[8], hi[8];
#pragma unroll
        for (int i = 0; i < 8; ++i) {
            lo[i] = cadd(a[i], a[i+8]);
            hi[i] = csub(a[i], a[i+8]);
        }
        if (!INV) {
            hi[1] = cmul(hi[1], make_float2( C16A, -S16A));
            hi[2] = mW81(hi[2]);
            hi[3] = cmul(hi[3], make_float2( S16A, -C16A));
            hi[4] = mNI (hi[4]);
            hi[5] = cmul(hi[5], make_float2(-S16A, -C16A));
            hi[6] = mW83(hi[6]);
            hi[7] = cmul(hi[7], make_float2(-C16A, -S16A));
            net8_fwd(lo); net8_fwd(hi);
        } else {
            hi[1] = cmul(hi[1], make_float2( C16A,  S16A));
            hi[2] = mW81c(hi[2]);
            hi[3] = cmul(hi[3], make_float2( S16A,  C16A));
            hi[4] = mPI (hi[4]);
            hi[5] = cmul(hi[5], make_float2(-S16A,  C16A));
            hi[6] = mW83c(hi[6]);
            hi[7] = cmul(hi[7], make_float2(-C16A,  S16A));
            net8_inv(lo); net8_inv(hi);
        }
        const int rev3[8] = {0,4,2,6,1,5,3,7};
#pragma unroll
        for (int s2 = 0; s2 < 8; ++s2) {
            z[SW(b + 2*rev3[s2]    )] = lo[s2];
            z[SW(b + 2*rev3[s2] + 1)] = hi[s2];
        }
    }
}

__global__ __launch_bounds__(NT, 4) void kfft_kernel(const float* __restrict__ k,
                                                     float2* __restrict__ Kf) {
    __shared__ float2 z[NFFT];
    int h = blockIdx.x, tid = threadIdx.x;
    const float* kr = k + (size_t)h * LCONV;
#pragma unroll
    for (int jj = 0; jj < 8; ++jj) {
        int i = tid + NT*jj;
        z[SW(i)]         = make_float2(kr[i], 0.f);
        z[SW(i + LCONV)] = make_float2(0.f, 0.f);
    }
    stage8<1024, false>(z, tid);
    stage8<128,  false>(z, tid);
    stage8<16,   false>(z, tid);
    stage16<false>(z, tid);
    __syncthreads();
    const float invN = 1.0f / (float)NFFT;   // fold 1/N into Kf
    float2* out = Kf + (size_t)h * NFFT;
#pragma unroll
    for (int jj = 0; jj < 16; ++jj) {
        int i = tid + NT*jj;
        float2 v = z[SW(i)];
        out[i] = make_float2(v.x * invN, v.y * invN);
    }
}

__global__ __launch_bounds__(NT, 4) void conv_kernel(const float* __restrict__ x,
                                                     const float2* __restrict__ Kf,
                                                     const float* __restrict__ Dv,
                                                     float* __restrict__ y) {
    __shared__ float2 z[NFFT];
    int bid = blockIdx.x;
    int h = bid >> 3;          // 8 consecutive blocks share one h (L2/L3 reuse of Kf)
    int pb = bid & 7;
    int b0 = pb*2, b1 = pb*2 + 1;
    int tid = threadIdx.x;

    const float* x0 = x + ((size_t)b0 * HCH + h) * LCONV;
    const float* x1 = x + ((size_t)b1 * HCH + h) * LCONV;

#pragma unroll
    for (int jj = 0; jj < 8; ++jj) {
        int i = tid + NT*jj;
        z[SW(i)]         = make_float2(x0[i], x1[i]);
        z[SW(i + LCONV)] = make_float2(0.f, 0.f);
    }

    stage8<1024, false>(z, tid);
    stage8<128,  false>(z, tid);
    stage8<16,   false>(z, tid);
    stage16<false>(z, tid);

    __syncthreads();
    // skip connection folded into the spectrum: multiplier = Kf + d/N
    // (Kf already carries 1/N; k + d*delta0 has spectrum K^ + d)
    const float dN = Dv[h] * (1.0f / (float)NFFT);
    const float2* kf = Kf + (size_t)h * NFFT;
#pragma unroll
    for (int jj = 0; jj < 16; ++jj) {
        int i = tid + NT*jj;
        float2 m = kf[i];
        z[SW(i)] = cmul(z[SW(i)], make_float2(m.x + dN, m.y));
    }

    stage16<true>(z, tid);
    stage8<16,   true>(z, tid);
    stage8<128,  true>(z, tid);
    stage8<1024, true>(z, tid);

    __syncthreads();
    float* y0 = y + ((size_t)b0 * HCH + h) * LCONV;
    float* y1 = y + ((size_t)b1 * HCH + h) * LCONV;
#pragma unroll
    for (int jj = 0; jj < 8; ++jj) {
        int i = tid + NT*jj;
        float2 r = z[SW(i)];
        y0[i] = r.x;
        y1[i] = r.y;
    }
}

extern "C" void kernel_launch(void* const* d_in, const int* in_sizes, int n_in,
                              void* d_out, int out_size, void* d_ws, size_t ws_size,
                              hipStream_t stream) {
    const float* x  = (const float*)d_in[0];
    const float* k  = (const float*)d_in[1];
    const float* Dv = (const float*)d_in[2];
    float* y  = (float*)d_out;
    float2* Kf = (float2*)d_ws;   // HCH * NFFT * 8 B = 64 MB

    kfft_kernel<<<HCH, NT, 0, stream>>>(k, Kf);
    conv_kernel<<<HCH * (BATCH/2), NT, 0, stream>>>(x, Kf, Dv, y);
}